// Round 8
// baseline (70.357 us; speedup 1.0000x reference)
//
#include <hip/hip_runtime.h>

typedef float f32x4 __attribute__((ext_vector_type(4)));
typedef short short8 __attribute__((ext_vector_type(8)));

#define NTYPES 4

// ws layout (bytes):
//   [0,64)        meta ints: 0-3 counts, 4-7 cursors, 8-12 bases (bases[i]=meta[8+i])
//   [512,1024)    dump row (pad-node store sink)
//   [1024,...)    perm[ntiles*64] ints (pad slots = -1)
//   [402432,)     W1T bf16 [4][256][128]  W1T[t][hcol][k]
//   [664576,)     W2T bf16 [4][128][256]  W2T[t][ocol][h]
//   [1048576,)    Xs bf16, sorted+padded+tile-swizzled, ntiles*16384 B

static __device__ __forceinline__ unsigned short f2bf(float f) {
  union { float f; unsigned int u; } v; v.f = f;
  unsigned int u = v.u;
  unsigned int r = u + 0x7FFFu + ((u >> 16) & 1u);   // round-nearest-even
  return (unsigned short)(r >> 16);
}

#define LGKM_BAR() do { \
  asm volatile("s_waitcnt lgkmcnt(0)" ::: "memory"); \
  __builtin_amdgcn_s_barrier(); \
  __builtin_amdgcn_sched_barrier(0); } while (0)

// weight transpose+cast; block 0 also zeroes meta (replaces hipMemsetAsync node)
__global__ __launch_bounds__(256) void k_prep(const float* __restrict__ W1,
                                              const float* __restrict__ W2,
                                              unsigned short* __restrict__ W1T,
                                              unsigned short* __restrict__ W2T,
                                              int* __restrict__ meta) {
  if (blockIdx.x == 0 && threadIdx.x < 16) meta[threadIdx.x] = 0;
  int i = blockIdx.x * 256 + threadIdx.x;   // 0..131071
  int t = i >> 15, rem = i & 32767;
  {
    int c = rem >> 7, k = rem & 127;        // W1T[t][c][k] = W1[t][k][c]
    W1T[i] = f2bf(W1[(t << 15) + k * 256 + c]);
  }
  {
    int o = rem >> 8, h = rem & 255;        // W2T[t][o][h] = W2[t][h][o]
    W2T[i] = f2bf(W2[(t << 15) + h * 128 + o]);
  }
}

__global__ __launch_bounds__(256) void k_hist(const int* __restrict__ NT, int n,
                                              int* __restrict__ meta) {
  __shared__ int c[NTYPES];
  if (threadIdx.x < NTYPES) c[threadIdx.x] = 0;
  __syncthreads();
  int i = blockIdx.x * 256 + threadIdx.x;
  if (i < n) atomicAdd(&c[NT[i]], 1);
  __syncthreads();
  if (threadIdx.x < NTYPES && c[threadIdx.x] > 0)
    atomicAdd(&meta[threadIdx.x], c[threadIdx.x]);
}

// scatter + inline prefix (from final counts) + base publish + pad fill
__global__ __launch_bounds__(256) void k_scatter(const int* __restrict__ NT, int n,
                                                 int* __restrict__ meta,
                                                 int* __restrict__ perm) {
  __shared__ int cnt[NTYPES];
  __shared__ int cbase[NTYPES];
  __shared__ int sb[NTYPES + 1];
  if (threadIdx.x < NTYPES) cnt[threadIdx.x] = 0;
  if (threadIdx.x == 0) {
    int b = 0; sb[0] = 0;
    for (int t = 0; t < NTYPES; ++t) {
      b += (meta[t] + 63) & ~63;           // pad each segment to 64
      sb[t + 1] = b;
    }
  }
  __syncthreads();
  int i = blockIdx.x * 256 + threadIdx.x;
  int t = 0, r = 0;
  bool valid = (i < n);
  if (valid) { t = NT[i]; r = atomicAdd(&cnt[t], 1); }
  __syncthreads();
  if (threadIdx.x < NTYPES)
    cbase[threadIdx.x] = atomicAdd(&meta[4 + threadIdx.x], cnt[threadIdx.x]);
  __syncthreads();
  if (valid) perm[sb[t] + cbase[t] + r] = i;
  if (blockIdx.x == 0) {
    if (threadIdx.x <= NTYPES) meta[8 + threadIdx.x] = sb[threadIdx.x];
    int tt = threadIdx.x >> 6, j = threadIdx.x & 63;   // pad count per type <= 63
    int p = sb[tt] + meta[tt] + j;
    if (p < sb[tt + 1]) perm[p] = -1;
  }
}

// Physically permute X -> Xs: bf16, sorted order, padded rows zeroed,
// tile-swizzled: within 16KB tile, byte = (r*256 + chunk*16) ^ ((r&7)<<4).
// This keeps the perm->X dependent-load chain OUT of the MFMA kernel; k_mlpw
// then stages linearly with global_load_lds (round-5 structure, measured fast;
// round-7's in-kernel gather was +35us of exposed latency).
__global__ __launch_bounds__(512) void k_sort(const float* __restrict__ X,
                                              const int* __restrict__ perm,
                                              const int* __restrict__ meta,
                                              unsigned short* __restrict__ Xs) {
  const int tid = threadIdx.x;
  const int r = tid >> 3;            // sorted row within tile, 0..63
  const int c = tid & 7;             // chunk group
  const int p = blockIdx.x * 64 + r;
  if (p >= meta[12]) return;
  const int rid = perm[p];
  char* xt = (char*)(Xs + (size_t)blockIdx.x * 8192);
  #pragma unroll
  for (int q = 0; q < 2; ++q) {
    int cc = c + q * 8;              // 16B-chunk index 0..15 (8 bf16)
    short8 u = {0, 0, 0, 0, 0, 0, 0, 0};
    if (rid >= 0) {
      const float* src = X + (size_t)rid * 128 + cc * 8;
      float4 v0 = *(const float4*)(src);
      float4 v1 = *(const float4*)(src + 4);
      u[0] = (short)f2bf(v0.x); u[1] = (short)f2bf(v0.y);
      u[2] = (short)f2bf(v0.z); u[3] = (short)f2bf(v0.w);
      u[4] = (short)f2bf(v1.x); u[5] = (short)f2bf(v1.y);
      u[6] = (short)f2bf(v1.z); u[7] = (short)f2bf(v1.w);
    }
    int byte = (r * 256 + cc * 16) ^ ((r & 7) << 4);
    *(short8*)(xt + byte) = u;
  }
}

// Weights-stationary persistent MLP. Grid = 512 blocks (2/CU), 128 blocks/type.
// Block handles tiles lb, lb+128, ... of its type; W1/W2 fragment slices live
// in registers across the whole tile loop. X staged by global_load_lds from
// pre-swizzled Xs (dbuf, counted vmcnt, raw s_barrier).
// __launch_bounds__(512, 2): VGPR cap 256 — REQUIRED. (512,4) => 64-VGPR
// target => weight frags spill to scratch (+100MB FETCH, round-6 regression).
__global__ __launch_bounds__(512, 2) void k_mlpw(
    const unsigned short* __restrict__ Xs, const int* __restrict__ perm,
    const int* __restrict__ meta,
    const unsigned short* __restrict__ W1T, const unsigned short* __restrict__ W2T,
    const float* __restrict__ B1, const float* __restrict__ B2,
    float* __restrict__ OUT, float* __restrict__ dump) {
  __shared__ __align__(16) unsigned char x_lds[2][16384];  // dbuf x tile (bf16, swizzled)
  __shared__ __align__(16) unsigned char h_lds[32768];     // h bf16; reused as out f32

  const int tid = threadIdx.x;
  const int l  = tid & 63, w = tid >> 6;   // wave 0..7
  const int lo = l & 15,  hi = l >> 4;

  const int t  = blockIdx.x >> 7;          // 128 blocks per type
  const int lb = blockIdx.x & 127;
  const int g0 = meta[8 + t] >> 6;         // first tile of this type
  const int g1 = meta[9 + t] >> 6;         // one past last
  const int nt = g1 - g0 - lb;
  if (nt <= 0) return;
  const int cnt = (nt + 127) >> 7;

  // ---- stage first tile (2 x global_load_lds width-16 per thread) ----
  {
    const unsigned short* s0 = Xs + (size_t)(g0 + lb) * 8192 + w * 512 + l * 8;
    __builtin_amdgcn_global_load_lds(
        (const __attribute__((address_space(1))) unsigned int*)s0,
        (__attribute__((address_space(3))) unsigned int*)(&x_lds[0][0] + w * 1024), 16, 0, 0);
    __builtin_amdgcn_global_load_lds(
        (const __attribute__((address_space(1))) unsigned int*)(s0 + 4096),
        (__attribute__((address_space(3))) unsigned int*)(&x_lds[0][0] + 8192 + w * 1024), 16, 0, 0);
  }

  // ---- weights + biases into registers, once per block ----
  const unsigned short* w1t = W1T + (t << 15);
  const unsigned short* w2t = W2T + (t << 15);
  short8 a1[4][2], a2[8];
  #pragma unroll
  for (int ks = 0; ks < 4; ++ks)
    #pragma unroll
    for (int m = 0; m < 2; ++m)
      a1[ks][m] = *(const short8*)(w1t + (w * 32 + m * 16 + lo) * 128 + ks * 32 + hi * 8);
  #pragma unroll
  for (int ks = 0; ks < 8; ++ks)
    a2[ks] = *(const short8*)(w2t + (w * 16 + lo) * 256 + ks * 32 + hi * 8);
  f32x4 bb1[2], bb2;
  #pragma unroll
  for (int m = 0; m < 2; ++m)
    bb1[m] = *(const f32x4*)(B1 + t * 256 + w * 32 + m * 16 + hi * 4);
  bb2 = *(const f32x4*)(B2 + t * 128 + w * 16 + hi * 4);

  for (int j = 0; j < cnt; ++j) {
    const int g = g0 + lb + j * 128;
    const bool hn = (j + 1 < cnt);

    // issue next tile's stage before waiting on current (keeps HBM busy)
    if (hn) {
      const unsigned short* s0 = Xs + (size_t)(g + 128) * 8192 + w * 512 + l * 8;
      unsigned char* d0 = &x_lds[(j + 1) & 1][0];
      __builtin_amdgcn_global_load_lds(
          (const __attribute__((address_space(1))) unsigned int*)s0,
          (__attribute__((address_space(3))) unsigned int*)(d0 + w * 1024), 16, 0, 0);
      __builtin_amdgcn_global_load_lds(
          (const __attribute__((address_space(1))) unsigned int*)(s0 + 4096),
          (__attribute__((address_space(3))) unsigned int*)(d0 + 8192 + w * 1024), 16, 0, 0);
    }

    // counted vmcnt: tile-j x-loads retired (in-order retirement).
    // ops newer than tile-j's 2 loads: j==0: {next 2}; j>0: {rid 4, stores 4, next 2}.
    if (j == 0) {
      if (hn) asm volatile("s_waitcnt vmcnt(2)" ::: "memory");
      else    asm volatile("s_waitcnt vmcnt(0)" ::: "memory");
    } else {
      if (hn) asm volatile("s_waitcnt vmcnt(10)" ::: "memory");
      else    asm volatile("s_waitcnt vmcnt(8)" ::: "memory");
    }
    __builtin_amdgcn_s_barrier();
    __builtin_amdgcn_sched_barrier(0);

    const unsigned char* xb = &x_lds[j & 1][0];

    // ---- layer 1: W1 frags in regs (A), x from LDS (B) ----
    f32x4 acc[2][4];
    #pragma unroll
    for (int m = 0; m < 2; ++m)
      #pragma unroll
      for (int n = 0; n < 4; ++n) acc[m][n] = (f32x4){0.f, 0.f, 0.f, 0.f};
    #pragma unroll
    for (int ks = 0; ks < 4; ++ks) {
      const int k8 = ks * 32 + hi * 8;
      short8 b[4];
      #pragma unroll
      for (int n = 0; n < 4; ++n) {
        int row = n * 16 + lo;
        int byte = (row * 256 + k8 * 2) ^ ((row & 7) << 4);
        b[n] = *(const short8*)(xb + byte);
      }
      #pragma unroll
      for (int m = 0; m < 2; ++m)
        #pragma unroll
        for (int n = 0; n < 4; ++n)
          acc[m][n] = __builtin_amdgcn_mfma_f32_16x16x32_bf16(a1[ks][m], b[n], acc[m][n], 0, 0, 0);
    }

    // bias + relu -> h LDS (lane owns 4 consecutive hcols -> b64 writes)
    #pragma unroll
    for (int m = 0; m < 2; ++m) {
      const int hc = w * 32 + m * 16 + hi * 4;
      #pragma unroll
      for (int n = 0; n < 4; ++n) {
        int row = n * 16 + lo;
        ushort4 hv;
        hv.x = f2bf(fmaxf(acc[m][n][0] + bb1[m][0], 0.f));
        hv.y = f2bf(fmaxf(acc[m][n][1] + bb1[m][1], 0.f));
        hv.z = f2bf(fmaxf(acc[m][n][2] + bb1[m][2], 0.f));
        hv.w = f2bf(fmaxf(acc[m][n][3] + bb1[m][3], 0.f));
        int byte = (row * 512 + hc * 2) ^ ((row & 7) << 4);
        *(ushort4*)(h_lds + byte) = hv;
      }
    }
    LGKM_BAR();   // h visible; x_lds reads done

    // ---- layer 2: W2 frags in regs (A), h from LDS (B) ----
    f32x4 acc2[4];
    #pragma unroll
    for (int n = 0; n < 4; ++n) acc2[n] = (f32x4){0.f, 0.f, 0.f, 0.f};
    #pragma unroll
    for (int ks = 0; ks < 8; ++ks) {
      const int k8 = ks * 32 + hi * 8;
      short8 b[4];
      #pragma unroll
      for (int n = 0; n < 4; ++n) {
        int row = n * 16 + lo;
        int byte = (row * 512 + k8 * 2) ^ ((row & 7) << 4);
        b[n] = *(const short8*)(h_lds + byte);
      }
      #pragma unroll
      for (int n = 0; n < 4; ++n)
        acc2[n] = __builtin_amdgcn_mfma_f32_16x16x32_bf16(a2[ks], b[n], acc2[n], 0, 0, 0);
    }

    // rowids for the store phase (4 per thread)
    int rid[4];
    #pragma unroll
    for (int p = 0; p < 4; ++p) rid[p] = perm[g * 64 + p * 16 + (tid >> 5)];

    LGKM_BAR();   // all h reads done -> safe to overwrite h_lds with out f32

    // out f32 -> LDS (lane owns 4 consecutive ocols, swizzled rows)
    #pragma unroll
    for (int n = 0; n < 4; ++n) {
      int row = n * 16 + lo;
      const int oc = w * 16 + hi * 4;
      f32x4 o = acc2[n];
      o[0] += bb2[0]; o[1] += bb2[1]; o[2] += bb2[2]; o[3] += bb2[3];
      int byte = (row * 512 + oc * 4) ^ ((row & 7) << 4);
      *(f32x4*)(h_lds + byte) = o;
    }
    LGKM_BAR();   // out tile visible

    // row-coalesced scatter: 32 consecutive lanes write one contiguous 512B row
    #pragma unroll
    for (int p = 0; p < 4; ++p) {
      int off = p * 8192 + tid * 16;
      int row = off >> 9;
      f32x4 v = *(const f32x4*)(h_lds + (off ^ ((row & 7) << 4)));
      int colf = (off & 511) >> 2;
      float* dst = (rid[p] >= 0) ? (OUT + (size_t)rid[p] * 128 + colf) : (dump + colf);
      *(f32x4*)dst = v;   // always 4 stores/thread: keeps vmcnt accounting exact
    }
    // global stores overlap next tile's staging (no vmcnt drain in LGKM_BAR)
  }
}

extern "C" void kernel_launch(void* const* d_in, const int* in_sizes, int n_in,
                              void* d_out, int out_size, void* d_ws, size_t ws_size,
                              hipStream_t stream) {
  const float* X  = (const float*)d_in[0];
  const int*   NT = (const int*)d_in[1];
  const float* W1 = (const float*)d_in[2];
  const float* B1 = (const float*)d_in[3];
  const float* W2 = (const float*)d_in[4];
  const float* B2 = (const float*)d_in[5];
  float* OUT = (float*)d_out;
  const int n = in_sizes[1];

  char* ws = (char*)d_ws;
  int* meta = (int*)ws;                                   // counts/cursors/bases
  float* dump = (float*)(ws + 512);
  int* perm = (int*)(ws + 1024);
  unsigned short* W1T = (unsigned short*)(ws + 402432);
  unsigned short* W2T = (unsigned short*)(ws + 664576);
  unsigned short* Xs  = (unsigned short*)(ws + 1048576);

  const int ntiles = (n + 63) / 64 + NTYPES;              // worst-case padded tiles

  k_prep<<<512, 256, 0, stream>>>(W1, W2, W1T, W2T, meta);
  const int nb = (n + 255) / 256;
  k_hist<<<nb, 256, 0, stream>>>(NT, n, meta);
  k_scatter<<<nb, 256, 0, stream>>>(NT, n, meta, perm);
  k_sort<<<ntiles, 512, 0, stream>>>(X, perm, meta, Xs);
  k_mlpw<<<512, 512, 0, stream>>>(Xs, perm, meta, W1T, W2T, B1, B2, OUT, dump);
}

// Round 9
// 59.586 us; speedup vs baseline: 1.1808x; 1.1808x over previous
//
#include <hip/hip_runtime.h>

typedef float f32x4 __attribute__((ext_vector_type(4)));
typedef short short8 __attribute__((ext_vector_type(8)));

#define NTYPES 4

// ws layout (bytes):
//   [0,64)        meta ints: 0-3 counts, 4-7 cursors, 8-12 bases (bases[i]=meta[8+i])
//   [512,1024)    dump row (pad-node store sink)
//   [1024,...)    perm[ntiles*64] ints (pad slots = -1)
//   [402432,)     W1T bf16 [4][256][128]  W1T[t][hcol][k]
//   [664576,)     W2T bf16 [4][128][256]  W2T[t][ocol][h]

static __device__ __forceinline__ unsigned short f2bf(float f) {
  union { float f; unsigned int u; } v; v.f = f;
  unsigned int u = v.u;
  unsigned int r = u + 0x7FFFu + ((u >> 16) & 1u);   // round-nearest-even
  return (unsigned short)(r >> 16);
}

#define LGKM_BAR() do { \
  asm volatile("s_waitcnt lgkmcnt(0)" ::: "memory"); \
  __builtin_amdgcn_s_barrier(); \
  __builtin_amdgcn_sched_barrier(0); } while (0)

// Coalesced 64x64 LDS-tiled transpose+cast for W1->W1T, W2->W2T.
// (Old k_prep read W1/W2 at 1KB stride: uncoalesced 4B granules.)
// Block 0 also zeroes meta. Grid = 64 blocks: 0-31 W1 tiles, 32-63 W2 tiles.
__global__ __launch_bounds__(256) void k_prep(const float* __restrict__ W1,
                                              const float* __restrict__ W2,
                                              unsigned short* __restrict__ W1T,
                                              unsigned short* __restrict__ W2T,
                                              int* __restrict__ meta) {
  __shared__ unsigned short s[64][72];   // +8 pad: transpose-read conflicts
  const int tid = threadIdx.x;
  const int b = blockIdx.x;
  if (b == 0 && tid < 16) meta[tid] = 0;
  const int bb = b & 31;
  const int t = bb >> 3, ti = bb & 7;    // type, tile within type
  const float* src; unsigned short* dst; int scols, tr, tc;
  if (b < 32) { src = W1 + t * 32768; dst = W1T + t * 32768; scols = 256; tr = ti >> 2; tc = ti & 3; }
  else        { src = W2 + t * 32768; dst = W2T + t * 32768; scols = 128; tr = ti >> 1; tc = ti & 1; }
  const int srows = 32768 / scols;       // dst row length
  const int r0 = tid >> 4, c4 = (tid & 15) << 2;
  #pragma unroll
  for (int i = 0; i < 4; ++i) {
    int r = tr * 64 + i * 16 + r0;
    float4 v = *(const float4*)(src + r * scols + tc * 64 + c4);
    s[i * 16 + r0][c4 + 0] = f2bf(v.x);
    s[i * 16 + r0][c4 + 1] = f2bf(v.y);
    s[i * 16 + r0][c4 + 2] = f2bf(v.z);
    s[i * 16 + r0][c4 + 3] = f2bf(v.w);
  }
  __syncthreads();
  #pragma unroll
  for (int i = 0; i < 4; ++i) {
    int orow = i * 16 + r0;              // local dst row (= src col)
    ushort4 u;
    u.x = s[c4 + 0][orow];
    u.y = s[c4 + 1][orow];
    u.z = s[c4 + 2][orow];
    u.w = s[c4 + 3][orow];
    *(ushort4*)(dst + (tc * 64 + orow) * srows + tr * 64 + c4) = u;
  }
}

__global__ __launch_bounds__(256) void k_hist(const int* __restrict__ NT, int n,
                                              int* __restrict__ meta) {
  __shared__ int c[NTYPES];
  if (threadIdx.x < NTYPES) c[threadIdx.x] = 0;
  __syncthreads();
  int i = blockIdx.x * 256 + threadIdx.x;
  if (i < n) atomicAdd(&c[NT[i]], 1);
  __syncthreads();
  if (threadIdx.x < NTYPES && c[threadIdx.x] > 0)
    atomicAdd(&meta[threadIdx.x], c[threadIdx.x]);
}

// scatter + inline prefix (from final counts) + base publish + pad fill
__global__ __launch_bounds__(256) void k_scatter(const int* __restrict__ NT, int n,
                                                 int* __restrict__ meta,
                                                 int* __restrict__ perm) {
  __shared__ int cnt[NTYPES];
  __shared__ int cbase[NTYPES];
  __shared__ int sb[NTYPES + 1];
  if (threadIdx.x < NTYPES) cnt[threadIdx.x] = 0;
  if (threadIdx.x == 0) {
    int b = 0; sb[0] = 0;
    for (int t = 0; t < NTYPES; ++t) {
      b += (meta[t] + 63) & ~63;           // pad each segment to 64
      sb[t + 1] = b;
    }
  }
  __syncthreads();
  int i = blockIdx.x * 256 + threadIdx.x;
  int t = 0, r = 0;
  bool valid = (i < n);
  if (valid) { t = NT[i]; r = atomicAdd(&cnt[t], 1); }
  __syncthreads();
  if (threadIdx.x < NTYPES)
    cbase[threadIdx.x] = atomicAdd(&meta[4 + threadIdx.x], cnt[threadIdx.x]);
  __syncthreads();
  if (valid) perm[sb[t] + cbase[t] + r] = i;
  if (blockIdx.x == 0) {
    if (threadIdx.x <= NTYPES) meta[8 + threadIdx.x] = sb[threadIdx.x];
    int tt = threadIdx.x >> 6, j = threadIdx.x & 63;   // pad count per type <= 63
    int p = sb[tt] + meta[tt] + j;
    if (p < sb[tt + 1]) perm[p] = -1;
  }
}

// Weights-stationary persistent MLP with PIPELINED in-register X gather (T14).
// Grid = 512 blocks (2/CU at VGPR<=128), 128 blocks/type. W1/W2 fragment
// slices live in registers across the tile loop. Per tile:
//   cvt+ds_write xv -> BAR -> prefetch perm[j+1] -> L1 -> h-write -> BAR ->
//   L2 -> rid loads -> BAR -> out->LDS (acc2 dies) -> ISSUE X[j+1] gather ->
//   BAR -> row-coalesced store; xv = nv.
// Barriers are lgkm-only: global loads/stores stay in flight across them.
// __launch_bounds__(512, 2) REQUIRED: (512,4) => 64-VGPR target => weight
// frags spill to scratch (+100MB FETCH, round-6 regression).
__global__ __launch_bounds__(512, 2) void k_mlpw(
    const float* __restrict__ X, const int* __restrict__ perm,
    const int* __restrict__ meta,
    const unsigned short* __restrict__ W1T, const unsigned short* __restrict__ W2T,
    const float* __restrict__ B1, const float* __restrict__ B2,
    float* __restrict__ OUT, float* __restrict__ dump) {
  __shared__ __align__(16) unsigned char x_lds[16384];   // x tile bf16 (swizzled)
  __shared__ __align__(16) unsigned char h_lds[32768];   // h bf16; reused as out f32

  const int tid = threadIdx.x;
  const int l  = tid & 63, w = tid >> 6;   // wave 0..7
  const int lo = l & 15,  hi = l >> 4;

  const int t  = blockIdx.x >> 7;          // 128 blocks per type
  const int lb = blockIdx.x & 127;
  const int g0 = meta[8 + t] >> 6;         // first tile of this type
  const int g1 = meta[9 + t] >> 6;         // one past last
  const int nt = g1 - g0 - lb;
  if (nt <= 0) return;
  const int cnt = (nt + 127) >> 7;

  const int gr = tid >> 3;           // gather row 0..63
  const int gq = tid & 7;            // 16-float column group

  // ---- prologue: gather tile 0 (longest-latency chain issued first) ----
  int pm = perm[(g0 + lb) * 64 + gr];
  float4 xv0 = make_float4(0.f, 0.f, 0.f, 0.f), xv1 = xv0, xv2 = xv0, xv3 = xv0;
  if (pm >= 0) {
    const float4* s = (const float4*)(X + (size_t)pm * 128 + gq * 16);
    xv0 = s[0]; xv1 = s[1]; xv2 = s[2]; xv3 = s[3];
  }

  // ---- weights + biases into registers, once per block ----
  const unsigned short* w1t = W1T + (t << 15);
  const unsigned short* w2t = W2T + (t << 15);
  short8 a1[4][2], a2[8];
  #pragma unroll
  for (int ks = 0; ks < 4; ++ks)
    #pragma unroll
    for (int m = 0; m < 2; ++m)
      a1[ks][m] = *(const short8*)(w1t + (w * 32 + m * 16 + lo) * 128 + ks * 32 + hi * 8);
  #pragma unroll
  for (int ks = 0; ks < 8; ++ks)
    a2[ks] = *(const short8*)(w2t + (w * 16 + lo) * 256 + ks * 32 + hi * 8);
  f32x4 bb1[2], bb2;
  #pragma unroll
  for (int m = 0; m < 2; ++m)
    bb1[m] = *(const f32x4*)(B1 + t * 256 + w * 32 + m * 16 + hi * 4);
  bb2 = *(const f32x4*)(B2 + t * 128 + w * 16 + hi * 4);

  for (int j = 0; j < cnt; ++j) {
    const int g = g0 + lb + j * 128;
    const bool hn = (j + 1 < cnt);

    // ---- x regs -> bf16 swizzled LDS ----
    {
      short8 c0, c1;
      c0[0] = (short)f2bf(xv0.x); c0[1] = (short)f2bf(xv0.y);
      c0[2] = (short)f2bf(xv0.z); c0[3] = (short)f2bf(xv0.w);
      c0[4] = (short)f2bf(xv1.x); c0[5] = (short)f2bf(xv1.y);
      c0[6] = (short)f2bf(xv1.z); c0[7] = (short)f2bf(xv1.w);
      c1[0] = (short)f2bf(xv2.x); c1[1] = (short)f2bf(xv2.y);
      c1[2] = (short)f2bf(xv2.z); c1[3] = (short)f2bf(xv2.w);
      c1[4] = (short)f2bf(xv3.x); c1[5] = (short)f2bf(xv3.y);
      c1[6] = (short)f2bf(xv3.z); c1[7] = (short)f2bf(xv3.w);
      const int base = gr * 256 + gq * 32;
      const int swz = (gr & 7) << 4;
      *(short8*)(x_lds + (base ^ swz)) = c0;
      *(short8*)(x_lds + ((base + 16) ^ swz)) = c1;
    }
    LGKM_BAR();   // x tile visible

    // prefetch next tile's perm NOW: its latency hides under L1+L2
    int pm2 = -1;
    if (hn) pm2 = perm[(g + 128) * 64 + gr];

    // ---- layer 1: W1 frags in regs (A), x from LDS (B) ----
    f32x4 acc[2][4];
    #pragma unroll
    for (int m = 0; m < 2; ++m)
      #pragma unroll
      for (int n = 0; n < 4; ++n) acc[m][n] = (f32x4){0.f, 0.f, 0.f, 0.f};
    #pragma unroll
    for (int ks = 0; ks < 4; ++ks) {
      const int k8 = ks * 32 + hi * 8;
      short8 b[4];
      #pragma unroll
      for (int n = 0; n < 4; ++n) {
        int row = n * 16 + lo;
        int byte = (row * 256 + k8 * 2) ^ ((row & 7) << 4);
        b[n] = *(const short8*)(x_lds + byte);
      }
      #pragma unroll
      for (int m = 0; m < 2; ++m)
        #pragma unroll
        for (int n = 0; n < 4; ++n)
          acc[m][n] = __builtin_amdgcn_mfma_f32_16x16x32_bf16(a1[ks][m], b[n], acc[m][n], 0, 0, 0);
    }

    // bias + relu -> h LDS (lane owns 4 consecutive hcols -> b64 writes)
    #pragma unroll
    for (int m = 0; m < 2; ++m) {
      const int hc = w * 32 + m * 16 + hi * 4;
      #pragma unroll
      for (int n = 0; n < 4; ++n) {
        int row = n * 16 + lo;
        ushort4 hv;
        hv.x = f2bf(fmaxf(acc[m][n][0] + bb1[m][0], 0.f));
        hv.y = f2bf(fmaxf(acc[m][n][1] + bb1[m][1], 0.f));
        hv.z = f2bf(fmaxf(acc[m][n][2] + bb1[m][2], 0.f));
        hv.w = f2bf(fmaxf(acc[m][n][3] + bb1[m][3], 0.f));
        int byte = (row * 512 + hc * 2) ^ ((row & 7) << 4);
        *(ushort4*)(h_lds + byte) = hv;
      }
    }
    LGKM_BAR();   // h visible; x reads retired

    // ---- layer 2: W2 frags in regs (A), h from LDS (B) ----
    f32x4 acc2[4];
    #pragma unroll
    for (int n = 0; n < 4; ++n) acc2[n] = (f32x4){0.f, 0.f, 0.f, 0.f};
    #pragma unroll
    for (int ks = 0; ks < 8; ++ks) {
      const int k8 = ks * 32 + hi * 8;
      short8 b[4];
      #pragma unroll
      for (int n = 0; n < 4; ++n) {
        int row = n * 16 + lo;
        int byte = (row * 512 + k8 * 2) ^ ((row & 7) << 4);
        b[n] = *(const short8*)(h_lds + byte);
      }
      #pragma unroll
      for (int n = 0; n < 4; ++n)
        acc2[n] = __builtin_amdgcn_mfma_f32_16x16x32_bf16(a2[ks], b[n], acc2[n], 0, 0, 0);
    }

    // rowids for the store phase (4 per thread)
    int rid[4];
    #pragma unroll
    for (int p = 0; p < 4; ++p) rid[p] = perm[g * 64 + p * 16 + (tid >> 5)];

    LGKM_BAR();   // all h reads done -> safe to overwrite h_lds with out f32

    // out f32 -> LDS (lane owns 4 consecutive ocols; acc2 dies here)
    #pragma unroll
    for (int n = 0; n < 4; ++n) {
      int row = n * 16 + lo;
      const int oc = w * 16 + hi * 4;
      f32x4 o = acc2[n];
      o[0] += bb2[0]; o[1] += bb2[1]; o[2] += bb2[2]; o[3] += bb2[3];
      int byte = (row * 512 + oc * 4) ^ ((row & 7) << 4);
      *(f32x4*)(h_lds + byte) = o;
    }

    // issue next tile's X gather now (acc2 dead -> nv fits the VGPR budget);
    // latency hides under the barrier + store phase + next loop-top cvt wait
    float4 nv0 = make_float4(0.f, 0.f, 0.f, 0.f), nv1 = nv0, nv2 = nv0, nv3 = nv0;
    if (pm2 >= 0) {
      const float4* s = (const float4*)(X + (size_t)pm2 * 128 + gq * 16);
      nv0 = s[0]; nv1 = s[1]; nv2 = s[2]; nv3 = s[3];
    }

    LGKM_BAR();   // out tile visible

    // row-coalesced scatter: 32 consecutive lanes write one contiguous 512B row
    #pragma unroll
    for (int p = 0; p < 4; ++p) {
      int off = p * 8192 + tid * 16;
      int row = off >> 9;
      f32x4 v = *(const f32x4*)(h_lds + (off ^ ((row & 7) << 4)));
      int colf = (off & 511) >> 2;
      float* dst = (rid[p] >= 0) ? (OUT + (size_t)rid[p] * 128 + colf) : (dump + colf);
      *(f32x4*)dst = v;
    }
    // global stores overlap next tile's cvt/ds_write (lgkm-only barriers)

    xv0 = nv0; xv1 = nv1; xv2 = nv2; xv3 = nv3;
  }
}

extern "C" void kernel_launch(void* const* d_in, const int* in_sizes, int n_in,
                              void* d_out, int out_size, void* d_ws, size_t ws_size,
                              hipStream_t stream) {
  const float* X  = (const float*)d_in[0];
  const int*   NT = (const int*)d_in[1];
  const float* W1 = (const float*)d_in[2];
  const float* B1 = (const float*)d_in[3];
  const float* W2 = (const float*)d_in[4];
  const float* B2 = (const float*)d_in[5];
  float* OUT = (float*)d_out;
  const int n = in_sizes[1];

  char* ws = (char*)d_ws;
  int* meta = (int*)ws;                                   // counts/cursors/bases
  float* dump = (float*)(ws + 512);
  int* perm = (int*)(ws + 1024);
  unsigned short* W1T = (unsigned short*)(ws + 402432);
  unsigned short* W2T = (unsigned short*)(ws + 664576);

  k_prep<<<64, 256, 0, stream>>>(W1, W2, W1T, W2T, meta);
  const int nb = (n + 255) / 256;
  k_hist<<<nb, 256, 0, stream>>>(NT, n, meta);
  k_scatter<<<nb, 256, 0, stream>>>(NT, n, meta, perm);
  k_mlpw<<<512, 512, 0, stream>>>(X, perm, meta, W1T, W2T, B1, B2, OUT, dump);
}